// Round 3
// 664.832 us; speedup vs baseline: 1.0043x; 1.0043x over previous
//
#include <hip/hip_runtime.h>
#include <cstdint>

#define HH 256
#define WW 256
#define PLANE (HH * WW)      // 65536
#define HALF 8
#define TEMP_INV 100.0f      // 1 / 0.01

__device__ __forceinline__ unsigned long long umax64(unsigned long long a,
                                                     unsigned long long b) {
    return a > b ? a : b;
}

// Order-preserving float->uint32: larger float => larger uint.
// Packed key: (key32 << 32) | ~idx  => max() prefers larger value, then SMALLER
// index on exact ties (matches jnp.argmax first-occurrence semantics).
__device__ __forceinline__ unsigned long long pack_key(float v, int idx) {
    unsigned int b = __float_as_uint(v);
    b = (b & 0x80000000u) ? ~b : (b | 0x80000000u);
    return ((unsigned long long)b << 32) | (unsigned int)(~(unsigned int)idx);
}

__global__ __launch_bounds__(256) void softargmax_kernel(
    const float* __restrict__ heat, float* __restrict__ out, int BC) {
    const int bc  = blockIdx.x;
    const int tid = threadIdx.x;
    const float* plane = heat + (size_t)bc * PLANE;

    // ---------------- Phase 1: argmax over the 256x256 plane ----------------
    // Hot loop is float-max only (v_max3 + v_max per float4) plus a 3-op
    // first-occurrence tracker of the winning float4 index. The expensive
    // 64-bit packed-key machinery runs once per thread after the loop.
    const float4* p4 = (const float4*)plane;  // 16384 float4s
    float cur   = -INFINITY;
    int   cur_i = 0;                          // float4 index of current max
#pragma unroll 8
    for (int k = 0; k < PLANE / 4 / 256; ++k) {   // 64 iterations, known trip
        const int i = tid + (k << 8);
        float4 v = p4[i];
        const float m = fmaxf(fmaxf(v.x, v.y), fmaxf(v.z, v.w));
        if (m > cur) { cur = m; cur_i = i; }      // strict > keeps FIRST max
    }
    // Recover the slot within the winning float4 (first occurrence: x,y,z,w).
    // One scattered 16B re-read per thread; hits L2/L3 (plane just streamed).
    const float4 wv = p4[cur_i];
    const int slot = (wv.x == cur) ? 0 : (wv.y == cur) ? 1 : (wv.z == cur) ? 2 : 3;
    unsigned long long best = pack_key(cur, cur_i * 4 + slot);

    // wave (64-lane) reduction
#pragma unroll
    for (int off = 32; off > 0; off >>= 1)
        best = umax64(best, __shfl_down(best, off, 64));

    __shared__ unsigned long long wmax[4];
    __shared__ unsigned long long blockmax;
    const int wave = tid >> 6;
    if ((tid & 63) == 0) wmax[wave] = best;
    __syncthreads();
    if (tid == 0)
        blockmax = umax64(umax64(wmax[0], wmax[1]), umax64(wmax[2], wmax[3]));
    __syncthreads();

    const unsigned long long m = blockmax;
    const int idx = (int)(~(unsigned int)(m & 0xFFFFFFFFull));
    unsigned int vb = (unsigned int)(m >> 32);
    vb = (vb & 0x80000000u) ? (vb ^ 0x80000000u) : ~vb;
    const float vmax = __uint_as_float(vb);

    const int x0 = idx & (WW - 1);
    const int y0 = idx >> 8;
    const int xmin = max(x0 - HALF, 0), xmax_ = min(x0 + HALF, WW);
    const int ymin = max(y0 - HALF, 0), ymax_ = min(y0 + HALF, HH);
    const int ww = xmax_ - xmin;
    const int wh = ymax_ - ymin;
    const int n  = ww * wh;  // <= 256

    // ------------- Phase 2: window softmax moments (shifted coords) ---------
    float s0 = 0.f, sx = 0.f, sy = 0.f, sxx = 0.f, syy = 0.f, sxy = 0.f;
    if (tid < n) {
        const int r  = tid / ww;
        const int c  = tid - r * ww;
        const int wy = ymin + r;
        const int wx = xmin + c;
        const float v = plane[wy * WW + wx];
        const float e = __expf((v - vmax) * TEMP_INV);  // <= 1, peak contributes 1
        const float dx = (float)(wx - x0);
        const float dy = (float)(wy - y0);
        s0  = e;
        sx  = e * dx;
        sy  = e * dy;
        sxx = e * dx * dx;
        syy = e * dy * dy;
        sxy = e * dx * dy;
    }
#pragma unroll
    for (int off = 32; off > 0; off >>= 1) {
        s0  += __shfl_down(s0,  off, 64);
        sx  += __shfl_down(sx,  off, 64);
        sy  += __shfl_down(sy,  off, 64);
        sxx += __shfl_down(sxx, off, 64);
        syy += __shfl_down(syy, off, 64);
        sxy += __shfl_down(sxy, off, 64);
    }
    __shared__ float ws[4][6];
    if ((tid & 63) == 0) {
        ws[wave][0] = s0;  ws[wave][1] = sx;  ws[wave][2] = sy;
        ws[wave][3] = sxx; ws[wave][4] = syy; ws[wave][5] = sxy;
    }
    __syncthreads();
    if (tid == 0) {
        const float t0  = ws[0][0] + ws[1][0] + ws[2][0] + ws[3][0];
        const float tx  = ws[0][1] + ws[1][1] + ws[2][1] + ws[3][1];
        const float ty  = ws[0][2] + ws[1][2] + ws[2][2] + ws[3][2];
        const float txx = ws[0][3] + ws[1][3] + ws[2][3] + ws[3][3];
        const float tyy = ws[0][4] + ws[1][4] + ws[2][4] + ws[3][4];
        const float txy = ws[0][5] + ws[1][5] + ws[2][5] + ws[3][5];
        const float inv = 1.0f / t0;
        const float mx = tx * inv;   // mean of dx
        const float my = ty * inv;   // mean of dy
        const float var_xx = txx * inv - mx * mx;
        const float var_yy = tyy * inv - my * my;
        const float cov_xy = txy * inv - mx * my;
        const float x_mean = (float)x0 + mx;
        const float y_mean = (float)y0 + my;

        // coords (B,C,2)
        out[bc * 2 + 0] = x_mean * (1.0f / (WW - 1));
        out[bc * 2 + 1] = y_mean * (1.0f / (HH - 1));
        // cov (B,C,2,2)
        float* cov = out + (size_t)BC * 2;
        cov[bc * 4 + 0] = var_xx;
        cov[bc * 4 + 1] = cov_xy;
        cov[bc * 4 + 2] = cov_xy;
        cov[bc * 4 + 3] = var_yy;
        // spread (B,C,1)
        float* spread = out + (size_t)BC * 6;
        spread[bc] = var_xx + var_yy;
    }
}

extern "C" void kernel_launch(void* const* d_in, const int* in_sizes, int n_in,
                              void* d_out, int out_size, void* d_ws, size_t ws_size,
                              hipStream_t stream) {
    const float* heat = (const float*)d_in[0];
    float* out = (float*)d_out;
    const int BC = in_sizes[0] / PLANE;  // 32*64 = 2048
    softargmax_kernel<<<dim3(BC), dim3(256), 0, stream>>>(heat, out, BC);
}